// Round 6
// baseline (13884.953 us; speedup 1.0000x reference)
//
#include <hip/hip_runtime.h>

// ---------------------------------------------------------------------------
// GRU forecaster: B=32, T=2048, I=256, H=512, L=2, O=64   (f16 datapath)
// BOTH LAYERS CONCURRENT in one cooperative scan (layer-1 runs ~1 exchange
// behind layer-0). 8 mega-clusters x 4 batches; grid = 8 x 24 = 192 WGs.
//  - A-WGs (role 0..7): layer-0 member m, j in [64m,+64); wave w owns k-chunk
//    [64w,+64); Wh0 chunk in VGPRs, shared by the 4 batches. Per step, per
//    batch q: poll h0[t-1] -> dots -> LDS deposit+flag; wave q finalizes
//    batch q and publishes h0[t] into a DEPTH-4 ring (tag16|f16, agent).
//  - B-WGs (role 8..23): layer-1 member mB, j in [32mB,+32); wave w owns
//    k-chunk [64w,+64) of Wh1 AND Wi1 (k-halved across lane pairs). Per step:
//    poll h1[t-1] + hh-dots (4 batches), then poll h0[t] + xi-dots + flag;
//    wave q finalizes batch q, publishes h1 (parity-2 mailbox).
//  - FLOW CONTROL (round-5 livelock fix): explicit progress arrays.
//    Prog1[b][16]: B-member stores t after publishing h1[t] (=> consumed
//    h0[t]).  ProgA[b][8]: A-member stores t after publishing h0[t] (=>
//    consumed h0[t-1]).  A publishes h0[t] over slot (t&3) (holds h0[t-4])
//    only when ALL ProgA >= t-3 and ALL Prog1 >= t-4 (one preloaded word
//    per lane, lanes 0..23, __all; preload hides the LLC latency).
//  - Per-batch stagger: batch q published ~(q+1)*384cy into the step;
//    consumers poll batches in the same order -> pipelined detect.
// h0seq + layer-1 GEMM + Wi1 transpose are deleted (xi1 computed in-scan).
// ---------------------------------------------------------------------------

typedef unsigned int  u32;
typedef unsigned short u16;
typedef float v4f __attribute__((ext_vector_type(4)));
typedef _Float16 v2h __attribute__((ext_vector_type(2)));
typedef _Float16 v8h __attribute__((ext_vector_type(8)));

#if defined(__has_builtin)
#  if __has_builtin(__builtin_amdgcn_fdot2)
#    define FDOT2(a, b, c) __builtin_amdgcn_fdot2((a), (b), (c), false)
#  endif
#endif
#ifndef FDOT2
#  define FDOT2(a, b, c) ((c) + (float)(a)[0] * (float)(b)[0] + (float)(a)[1] * (float)(b)[1])
#endif

__device__ __forceinline__ u16 f2h(float f) {
    _Float16 h = (_Float16)f;
    return *(u16*)&h;
}
__device__ __forceinline__ float h2f(u16 b) {
    _Float16 h = *(_Float16*)&b;
    return (float)h;
}
__device__ __forceinline__ u32 LDG(const u32* p) {
    return __hip_atomic_load(p, __ATOMIC_RELAXED, __HIP_MEMORY_SCOPE_AGENT);
}

// --------------------------- prep kernels ----------------------------------

// src fp32 [R][C] -> dst f16 [C][R]  (32x32 tiles)
__global__ __launch_bounds__(256) void transpose_cast(const float* __restrict__ src,
                                                      u16* __restrict__ dst,
                                                      int R, int C) {
    __shared__ u16 tile[32][33];
    int c0 = blockIdx.x * 32, r0 = blockIdx.y * 32;
    int t = threadIdx.x;
    {
        int rl = t >> 3, cl4 = (t & 7) * 4;
        float4 v = *(const float4*)&src[(size_t)(r0 + rl) * C + c0 + cl4];
        tile[rl][cl4 + 0] = f2h(v.x);
        tile[rl][cl4 + 1] = f2h(v.y);
        tile[rl][cl4 + 2] = f2h(v.z);
        tile[rl][cl4 + 3] = f2h(v.w);
    }
    __syncthreads();
    {
        int cl = t >> 3, rl4 = (t & 7) * 4;
        uint2 o;
        o.x = (u32)tile[rl4 + 0][cl] | ((u32)tile[rl4 + 1][cl] << 16);
        o.y = (u32)tile[rl4 + 2][cl] | ((u32)tile[rl4 + 3][cl] << 16);
        *(uint2*)&dst[(size_t)(c0 + cl) * R + r0 + rl4] = o;
    }
}

// Layer-0 pack (8 members, j64): uint4 index ((m*8+w)*24 + c)*64 + l,
// c = g*8+qk: holds k-pairs kb = w*64+qk*8, col = g*512 + m*64 + l.
__global__ __launch_bounds__(256) void pack_wh(const float* __restrict__ Wh,
                                               uint4* __restrict__ dst) {
    int id = blockIdx.x * 256 + threadIdx.x;   // < 98304
    int l = id & 63;
    int c = (id >> 6) % 24;
    int mw = id / 1536;                        // m*8 + w
    int m = mw >> 3, w = mw & 7;
    int g = c >> 3, qk = c & 7;
    int col = g * 512 + m * 64 + l;
    int kb = w * 64 + qk * 8;
    u32 d[4];
#pragma unroll
    for (int p = 0; p < 4; ++p) {
        u16 a = f2h(Wh[(size_t)(kb + 2 * p) * 1536 + col]);
        u16 b = f2h(Wh[(size_t)(kb + 2 * p + 1) * 1536 + col]);
        d[p] = (u32)a | ((u32)b << 16);
    }
    uint4 o; o.x = d[0]; o.y = d[1]; o.z = d[2]; o.w = d[3];
    dst[id] = o;
}

// Layer-1 pack (16 members, j32, lane khalf split): uint4 index
// ((mB*8+w)*12 + c)*64 + l, c = g*4+qk4: holds k-pairs
// kb = w*64 + (l>>5)*32 + qk4*8, col = g*512 + mB*32 + (l&31).
__global__ __launch_bounds__(256) void pack_whB(const float* __restrict__ Wh,
                                                uint4* __restrict__ dst) {
    int id = blockIdx.x * 256 + threadIdx.x;   // < 98304
    int l = id & 63;
    int c = (id >> 6) % 12;
    int mw = id / 768;                         // mB*8 + w
    int mB = mw >> 3, w = mw & 7;
    int g = c >> 2, qk4 = c & 3;
    int col = g * 512 + mB * 32 + (l & 31);
    int kb = w * 64 + (l >> 5) * 32 + qk4 * 8;
    u32 d[4];
#pragma unroll
    for (int p = 0; p < 4; ++p) {
        u16 a = f2h(Wh[(size_t)(kb + 2 * p) * 1536 + col]);
        u16 b = f2h(Wh[(size_t)(kb + 2 * p + 1) * 1536 + col]);
        d[p] = (u32)a | ((u32)b << 16);
    }
    uint4 o; o.x = d[0]; o.y = d[1]; o.z = d[2]; o.w = d[3];
    dst[id] = o;
}

// ---------------- GEMM: xi_chunk = A_rows @ Bt^T + bias -> f16 --------------
template <int K, bool AF32>
__global__ __launch_bounds__(256) void gemm_xi(const void* __restrict__ Ap,
                                               const u16* __restrict__ Bt,
                                               const float* __restrict__ bias,
                                               u16* __restrict__ C,
                                               int t0, int lgTc) {
    __shared__ u16 As[64 * 40];
    __shared__ u16 Bs[64 * 40];
    const int tid = threadIdx.x;
    const int n0 = blockIdx.x * 64;
    const int m0 = blockIdx.y * 64;
    const int row = tid >> 2, koff = (tid & 3) * 8;
    const int lane = tid & 63, w = tid >> 6;
    const int m = m0 + row;
    const int b = m >> lgTc;
    const int tl = m & ((1 << lgTc) - 1);
    const size_t srow = ((size_t)b << 11) + (size_t)(t0 + tl);
    v4f acc[4];
#pragma unroll
    for (int i = 0; i < 4; ++i) acc[i] = (v4f){0.f, 0.f, 0.f, 0.f};

    for (int k0 = 0; k0 < K; k0 += 32) {
        if (AF32) {
            const float* A = (const float*)Ap;
            float4 v0 = *(const float4*)&A[srow * K + k0 + koff];
            float4 v1 = *(const float4*)&A[srow * K + k0 + koff + 4];
            uint4 o;
            o.x = (u32)f2h(v0.x) | ((u32)f2h(v0.y) << 16);
            o.y = (u32)f2h(v0.z) | ((u32)f2h(v0.w) << 16);
            o.z = (u32)f2h(v1.x) | ((u32)f2h(v1.y) << 16);
            o.w = (u32)f2h(v1.z) | ((u32)f2h(v1.w) << 16);
            *(uint4*)&As[row * 40 + koff] = o;
        } else {
            const u16* A = (const u16*)Ap;
            *(uint4*)&As[row * 40 + koff] =
                *(const uint4*)&A[srow * K + k0 + koff];
        }
        *(uint4*)&Bs[row * 40 + koff] =
            *(const uint4*)&Bt[(size_t)(n0 + row) * K + k0 + koff];
        __syncthreads();
        v8h a = *(const v8h*)&As[(w * 16 + (lane & 15)) * 40 + (lane >> 4) * 8];
#pragma unroll
        for (int nt = 0; nt < 4; ++nt) {
            v8h bm = *(const v8h*)&Bs[(nt * 16 + (lane & 15)) * 40 + (lane >> 4) * 8];
            acc[nt] = __builtin_amdgcn_mfma_f32_16x16x32_f16(a, bm, acc[nt], 0, 0, 0);
        }
        __syncthreads();
    }
#pragma unroll
    for (int nt = 0; nt < 4; ++nt) {
        int col = n0 + nt * 16 + (lane & 15);
        float bv = bias[col];
#pragma unroll
        for (int rI = 0; rI < 4; ++rI) {
            int rowm = m0 + w * 16 + (lane >> 4) * 4 + rI;
            C[(size_t)rowm * 1536 + col] = f2h(acc[nt][rI] + bv);
        }
    }
}

// --------------------------- fused 2-layer GRU scan -------------------------
// grid = 192 x 512. mc = wg/24 (0..7, 4 batches), role = wg%24.
__global__ __launch_bounds__(512) void gru_scan2(const u16* __restrict__ xi,
                                                 const uint4* __restrict__ Wh0p,
                                                 const uint4* __restrict__ Wh1B,
                                                 const uint4* __restrict__ Wi1B,
                                                 const float* __restrict__ bi1,
                                                 const float* __restrict__ bhn0,
                                                 const float* __restrict__ bhn1,
                                                 u32* __restrict__ Hb0,
                                                 u32* __restrict__ Hb1,
                                                 u32* __restrict__ ProgA,
                                                 u32* __restrict__ Prog1,
                                                 float* __restrict__ h1last,
                                                 float* __restrict__ hstate0,
                                                 float* __restrict__ hstate1,
                                                 int t0, int Tc) {
    struct SA {
        u16 Sh[4][8][64];            // h0[t-1], per batch per k-chunk (wave-local)
        float P0[2][4][8][3][64];    // [parity][batch][wave][gate][j]
        u32 flag[2][4][8];
    };
    struct SB {
        u16 Sh1[4][8][64];           // h1[t-1]
        u16 Sh0[4][8][64];           // h0[t]
        float P1[2][4][8][6][32];    // [par][batch][wave][hr,hz,hn,xr,xz,xn][j]
        u32 flag[2][4][8];
    };
    union SU { SA a; SB b; };
    __shared__ __align__(16) SU S;

    const int tid = threadIdx.x;
    const int wg = blockIdx.x;
    const int mc = wg / 24;
    const int rr = wg % 24;
    const int W = tid >> 6, lane = tid & 63;
    const int tEnd = t0 + Tc;

    if (rr < 8) {
        // =================== A: layer 0, member m = rr =====================
        const int m = rr;
        if (tid < 64) ((u32*)S.a.flag)[tid] = 0;
        uint4 Wreg[24];
        {
            const uint4* src = Wh0p + ((size_t)(m * 8 + W) * 24) * 64 + lane;
#pragma unroll
            for (int c = 0; c < 24; ++c) Wreg[c] = src[c * 64];
        }
        const int j = m * 64 + lane;
        const int bq = mc * 4 + W;          // valid for W<4
        float bhnv = 0.f, hprev = 0.f;
        u16 rx = 0, rz = 0, rn = 0;
        const u32* gp = ProgA;               // guard pointer (W<4 only)
        u32 pgv = 0;                         // preloaded progress word
        if (W < 4) {
            bhnv = bhn0[j];
            if (t0 > 0) hprev = hstate0[bq * 512 + j];
            const u16* p = xi + ((size_t)bq * Tc) * 1536 + j;
            rx = p[0]; rz = p[512]; rn = p[1024];
            gp = (lane < 8)  ? (ProgA + bq * 8 + lane)
               : (lane < 24) ? (Prog1 + bq * 16 + (lane - 8))
                             : (ProgA + bq * 8);
            pgv = LDG(gp);
        }
        __syncthreads();   // flag init visible before loop

        for (int t = t0; t < tEnd; ++t) {
            const int pp = t & 1;
#pragma unroll
            for (int q = 0; q < 4; ++q) {
                // ---- poll h0[t-1] batch q, chunk W ----
                u16 hv = 0;
                if (t > 0) {
                    const u32 tg = (u32)(u16)t << 16;
                    const u32* p = Hb0 + (size_t)(mc * 4 + q) * 2048 +
                                   ((t - 1) & 3) * 512 + W * 64 + lane;
                    u32 v = 0;
                    for (int it = 0; it < 2000000; ++it) {
                        v = LDG(p);
                        if ((v & 0xFFFF0000u) == tg) break;
                        if (it > 16) __builtin_amdgcn_s_sleep(1);
                    }
                    hv = (u16)v;
                }
                S.a.Sh[q][W][lane] = hv;
                // ---- dots (wave-local LDS broadcast) ----
                float a0 = 0.f, a1 = 0.f, a2 = 0.f;
#pragma unroll
                for (int qk = 0; qk < 8; ++qk) {
                    v8h h8 = *(const v8h*)&S.a.Sh[q][W][qk * 8];
                    const v2h* hp = (const v2h*)&h8;
                    const v2h* p0 = (const v2h*)&Wreg[qk];
                    const v2h* p1 = (const v2h*)&Wreg[8 + qk];
                    const v2h* p2 = (const v2h*)&Wreg[16 + qk];
#pragma unroll
                    for (int p = 0; p < 4; ++p) {
                        a0 = FDOT2(p0[p], hp[p], a0);
                        a1 = FDOT2(p1[p], hp[p], a1);
                        a2 = FDOT2(p2[p], hp[p], a2);
                    }
                }
                S.a.P0[pp][q][W][0][lane] = a0;
                S.a.P0[pp][q][W][1][lane] = a1;
                S.a.P0[pp][q][W][2][lane] = a2;
                if (lane == 0)
                    __hip_atomic_store(&S.a.flag[pp][q][W], (u32)(t + 1),
                                       __ATOMIC_RELEASE, __HIP_MEMORY_SCOPE_WORKGROUP);
                // ---- wave q finalizes batch q ----
                if (W == q) {
                    for (int it = 0; it < 2000000; ++it) {
                        u32 fv = __hip_atomic_load(&S.a.flag[pp][q][lane & 7],
                                                   __ATOMIC_ACQUIRE, __HIP_MEMORY_SCOPE_WORKGROUP);
                        if (__all((lane >= 8) | (fv == (u32)(t + 1)))) break;
                        if (it > 16) __builtin_amdgcn_s_sleep(1);
                    }
                    float s0 = 0.f, s1 = 0.f, s2 = 0.f;
#pragma unroll
                    for (int w2 = 0; w2 < 8; ++w2) {
                        s0 += S.a.P0[pp][q][w2][0][lane];
                        s1 += S.a.P0[pp][q][w2][1][lane];
                        s2 += S.a.P0[pp][q][w2][2][lane];
                    }
                    float r = 1.f / (1.f + __expf(-(h2f(rx) + s0)));
                    float z = 1.f / (1.f + __expf(-(h2f(rz) + s1)));
                    float nx = h2f(rn) + r * (s2 + bhnv);
                    float n = 1.f - 2.f / (__expf(2.f * nx) + 1.f);   // tanh
                    float hn = (1.f - z) * n + z * hprev;
                    hprev = hn;
                    // ---- ring guard: ALL consumers done with h0[t-4] ----
                    if (t >= 4) {
                        const int thr = (lane < 8) ? (t - 3) : (t - 4);
                        if (!__all((lane >= 24) || ((int)pgv >= thr))) {
                            for (int it = 0; it < 2000000; ++it) {
                                pgv = LDG(gp);
                                if (__all((lane >= 24) || ((int)pgv >= thr))) break;
                                if (it > 8) __builtin_amdgcn_s_sleep(1);
                            }
                        }
                    }
                    __hip_atomic_store(Hb0 + (size_t)bq * 2048 + (t & 3) * 512 + j,
                                       ((u32)(u16)(t + 1) << 16) | (u32)f2h(hn),
                                       __ATOMIC_RELAXED, __HIP_MEMORY_SCOPE_AGENT);
                    if (lane == 0)
                        __hip_atomic_store(ProgA + bq * 8 + m, (u32)t,
                                           __ATOMIC_RELAXED, __HIP_MEMORY_SCOPE_AGENT);
                    pgv = LDG(gp);          // preload for next step (hidden)
                    if (t + 1 < tEnd) {     // prefetch xi for t+1
                        const u16* p = xi + ((size_t)bq * Tc + (t + 1 - t0)) * 1536 + j;
                        rx = p[0]; rz = p[512]; rn = p[1024];
                    }
                }
            }
        }
        if (W < 4) hstate0[bq * 512 + j] = hprev;
    } else {
        // =================== B: layer 1, member mB = rr-8 ==================
        const int mB = rr - 8;
        if (tid < 64) ((u32*)S.b.flag)[tid] = 0;
        uint4 Hreg[12], Xreg[12];
        {
            const uint4* hs = Wh1B + ((size_t)(mB * 8 + W) * 12) * 64 + lane;
            const uint4* xs = Wi1B + ((size_t)(mB * 8 + W) * 12) * 64 + lane;
#pragma unroll
            for (int c = 0; c < 12; ++c) { Hreg[c] = hs[c * 64]; Xreg[c] = xs[c * 64]; }
        }
        const int jB = mB * 32 + (lane & 31);
        const int kloc = (lane >> 5) * 32;
        const float b_r = bi1[jB], b_z = bi1[512 + jB], b_n = bi1[1024 + jB];
        const float bh = bhn1[jB];
        const int bq = mc * 4 + W;          // valid for W<4
        float hprev = 0.f;
        if (W < 4 && t0 > 0) hprev = hstate1[bq * 512 + jB];
        __syncthreads();

        for (int t = t0; t < tEnd; ++t) {
            const int pp = t & 1;
            // ---- phase 1: h1[t-1] polls + hh-dots, per batch -------------
#pragma unroll
            for (int q = 0; q < 4; ++q) {
                u16 hv = 0;
                if (t > 0) {
                    const u32 tg = (u32)(u16)t << 16;
                    const u32* p = Hb1 + (size_t)(mc * 4 + q) * 1024 +
                                   ((t - 1) & 1) * 512 + W * 64 + lane;
                    u32 v = 0;
                    for (int it = 0; it < 2000000; ++it) {
                        v = LDG(p);
                        if ((v & 0xFFFF0000u) == tg) break;
                        if (it > 16) __builtin_amdgcn_s_sleep(1);
                    }
                    hv = (u16)v;
                }
                S.b.Sh1[q][W][lane] = hv;
                float a0 = 0.f, a1 = 0.f, a2 = 0.f;
#pragma unroll
                for (int qk = 0; qk < 4; ++qk) {
                    v8h h8 = *(const v8h*)&S.b.Sh1[q][W][kloc + qk * 8];
                    const v2h* hp = (const v2h*)&h8;
                    const v2h* p0 = (const v2h*)&Hreg[qk];
                    const v2h* p1 = (const v2h*)&Hreg[4 + qk];
                    const v2h* p2 = (const v2h*)&Hreg[8 + qk];
#pragma unroll
                    for (int p = 0; p < 4; ++p) {
                        a0 = FDOT2(p0[p], hp[p], a0);
                        a1 = FDOT2(p1[p], hp[p], a1);
                        a2 = FDOT2(p2[p], hp[p], a2);
                    }
                }
                a0 += __shfl_xor(a0, 32);
                a1 += __shfl_xor(a1, 32);
                a2 += __shfl_xor(a2, 32);
                if (lane < 32) {
                    S.b.P1[pp][q][W][0][lane] = a0;
                    S.b.P1[pp][q][W][1][lane] = a1;
                    S.b.P1[pp][q][W][2][lane] = a2;
                }
            }
            // ---- phase 2: h0[t] polls + xi-dots + finalize, per batch ----
#pragma unroll
            for (int q = 0; q < 4; ++q) {
                u16 hv = 0;
                {
                    const u32 tg = (u32)(u16)(t + 1) << 16;
                    const u32* p = Hb0 + (size_t)(mc * 4 + q) * 2048 +
                                   (t & 3) * 512 + W * 64 + lane;
                    u32 v = 0;
                    for (int it = 0; it < 2000000; ++it) {
                        v = LDG(p);
                        if ((v & 0xFFFF0000u) == tg) break;
                        if (it > 16) __builtin_amdgcn_s_sleep(1);
                    }
                    hv = (u16)v;
                }
                S.b.Sh0[q][W][lane] = hv;
                float a0 = 0.f, a1 = 0.f, a2 = 0.f;
#pragma unroll
                for (int qk = 0; qk < 4; ++qk) {
                    v8h h8 = *(const v8h*)&S.b.Sh0[q][W][kloc + qk * 8];
                    const v2h* hp = (const v2h*)&h8;
                    const v2h* p0 = (const v2h*)&Xreg[qk];
                    const v2h* p1 = (const v2h*)&Xreg[4 + qk];
                    const v2h* p2 = (const v2h*)&Xreg[8 + qk];
#pragma unroll
                    for (int p = 0; p < 4; ++p) {
                        a0 = FDOT2(p0[p], hp[p], a0);
                        a1 = FDOT2(p1[p], hp[p], a1);
                        a2 = FDOT2(p2[p], hp[p], a2);
                    }
                }
                a0 += __shfl_xor(a0, 32);
                a1 += __shfl_xor(a1, 32);
                a2 += __shfl_xor(a2, 32);
                if (lane < 32) {
                    S.b.P1[pp][q][W][3][lane] = a0;
                    S.b.P1[pp][q][W][4][lane] = a1;
                    S.b.P1[pp][q][W][5][lane] = a2;
                }
                if (lane == 0)
                    __hip_atomic_store(&S.b.flag[pp][q][W], (u32)(t + 1),
                                       __ATOMIC_RELEASE, __HIP_MEMORY_SCOPE_WORKGROUP);
                if (W == q) {
                    for (int it = 0; it < 2000000; ++it) {
                        u32 fv = __hip_atomic_load(&S.b.flag[pp][q][lane & 7],
                                                   __ATOMIC_ACQUIRE, __HIP_MEMORY_SCOPE_WORKGROUP);
                        if (__all((lane >= 8) | (fv == (u32)(t + 1)))) break;
                        if (it > 16) __builtin_amdgcn_s_sleep(1);
                    }
                    const int lj = lane & 31;
                    float HR = 0.f, HZ = 0.f, HN = 0.f, XR = 0.f, XZ = 0.f, XN = 0.f;
#pragma unroll
                    for (int w2 = 0; w2 < 8; ++w2) {
                        HR += S.b.P1[pp][q][w2][0][lj];
                        HZ += S.b.P1[pp][q][w2][1][lj];
                        HN += S.b.P1[pp][q][w2][2][lj];
                        XR += S.b.P1[pp][q][w2][3][lj];
                        XZ += S.b.P1[pp][q][w2][4][lj];
                        XN += S.b.P1[pp][q][w2][5][lj];
                    }
                    if (lane < 32) {
                        float r = 1.f / (1.f + __expf(-(XR + b_r + HR)));
                        float z = 1.f / (1.f + __expf(-(XZ + b_z + HZ)));
                        float nx = XN + b_n + r * (HN + bh);
                        float n = 1.f - 2.f / (__expf(2.f * nx) + 1.f);   // tanh
                        float hn = (1.f - z) * n + z * hprev;
                        hprev = hn;
                        __hip_atomic_store(Hb1 + (size_t)bq * 1024 + (t & 1) * 512 + jB,
                                           ((u32)(u16)(t + 1) << 16) | (u32)f2h(hn),
                                           __ATOMIC_RELAXED, __HIP_MEMORY_SCOPE_AGENT);
                        if (t == 2047) h1last[bq * 512 + jB] = hn;
                    }
                    if (lane == 0)
                        __hip_atomic_store(Prog1 + bq * 16 + mB, (u32)t,
                                           __ATOMIC_RELAXED, __HIP_MEMORY_SCOPE_AGENT);
                }
            }
        }
        if (W < 4 && lane < 32) hstate1[bq * 512 + jB] = hprev;
    }
}

// --------------------------- final FC --------------------------------------
__global__ __launch_bounds__(64) void final_fc(const float* __restrict__ h1,
                                               const float* __restrict__ Wfc,
                                               const float* __restrict__ bfc,
                                               float* __restrict__ out) {
    int b = blockIdx.x, o = threadIdx.x;
    float acc = bfc[o];
    for (int k = 0; k < 512; ++k) acc += h1[b * 512 + k] * Wfc[k * 64 + o];
    out[b * 64 + o] = acc;
}

// --------------------------- launch ----------------------------------------

extern "C" void kernel_launch(void* const* d_in, const int* in_sizes, int n_in,
                              void* d_out, int out_size, void* d_ws, size_t ws_size,
                              hipStream_t stream) {
    const float* x    = (const float*)d_in[0];
    const float* Wi0  = (const float*)d_in[1];
    const float* bi0  = (const float*)d_in[2];
    const float* Wh0  = (const float*)d_in[3];
    const float* bhn0 = (const float*)d_in[4];
    const float* Wi1  = (const float*)d_in[5];
    const float* bi1  = (const float*)d_in[6];
    const float* Wh1  = (const float*)d_in[7];
    const float* bhn1 = (const float*)d_in[8];
    const float* Wfc  = (const float*)d_in[9];
    const float* bfc  = (const float*)d_in[10];
    float* out = (float*)d_out;
    (void)in_sizes; (void)n_in; (void)out_size;

    char* ws = (char*)d_ws;
    size_t off = 0;
    auto take = [&](size_t bytes) -> char* {
        char* p = ws + off;
        off = (off + bytes + 255) & ~(size_t)255;
        return p;
    };
    u16*  Wi0t  = (u16*)take(1536 * 256 * 2);
    uint4* Wh0p = (uint4*)take(98304 * 16);
    uint4* Wh1B = (uint4*)take(98304 * 16);
    uint4* Wi1B = (uint4*)take(98304 * 16);
    u32*  Hb0   = (u32*)take(32 * 2048 * 4);    // depth-4 ring
    u32*  Hb1   = (u32*)take(32 * 1024 * 4);    // parity-2
    u32*  ProgA = (u32*)take(32 * 8 * 4);
    u32*  Prog1 = (u32*)take(32 * 16 * 4);
    float* hstate0 = (float*)take(32 * 512 * 4);
    float* hstate1 = (float*)take(32 * 512 * 4);
    float* h1last  = (float*)take(32 * 512 * 4);
    size_t fixed_end = off;

    int Tc = 2048;
    if (ws_size > 0) {
        while (Tc > 128 &&
               fixed_end + (size_t)32 * Tc * 1536 * 2 > ws_size) Tc >>= 1;
    }
    int lgTc = 31 - __builtin_clz((u32)Tc);
    u16* xibuf = (u16*)take((size_t)32 * Tc * 1536 * 2);
    int nChunk = 2048 / Tc;

    // zero mailboxes + progress (tags absolute; fresh per launch/replay)
    hipMemsetAsync(Hb0, 0, 32 * 2048 * 4, stream);
    hipMemsetAsync(Hb1, 0, 32 * 1024 * 4, stream);
    hipMemsetAsync(ProgA, 0, 32 * 8 * 4, stream);
    hipMemsetAsync(Prog1, 0, 32 * 16 * 4, stream);

    // prep
    transpose_cast<<<dim3(48, 8), 256, 0, stream>>>(Wi0, Wi0t, 256, 1536);
    pack_wh<<<384, 256, 0, stream>>>(Wh0, Wh0p);
    pack_whB<<<384, 256, 0, stream>>>(Wh1, Wh1B);
    pack_whB<<<384, 256, 0, stream>>>(Wi1, Wi1B);

    for (int c = 0; c < nChunk; ++c) {
        int t0 = c * Tc;
        gemm_xi<256, true><<<dim3(24, Tc / 2), 256, 0, stream>>>(
            (const void*)x, Wi0t, bi0, xibuf, t0, lgTc);
        const u16* xi_p = xibuf;
        const uint4* wh0_p = Wh0p; const uint4* wh1_p = Wh1B; const uint4* wi1_p = Wi1B;
        const float* bi1_p = bi1; const float* bh0_p = bhn0; const float* bh1_p = bhn1;
        u32* hb0_p = Hb0; u32* hb1_p = Hb1; u32* pga_p = ProgA; u32* pg1_p = Prog1;
        float* h1l_p = h1last; float* st0_p = hstate0; float* st1_p = hstate1;
        int t0v = t0, Tcv = Tc;
        void* args[] = {&xi_p, &wh0_p, &wh1_p, &wi1_p, &bi1_p, &bh0_p, &bh1_p,
                        &hb0_p, &hb1_p, &pga_p, &pg1_p, &h1l_p, &st0_p, &st1_p,
                        &t0v, &Tcv};
        hipLaunchCooperativeKernel(gru_scan2, dim3(192), dim3(512), args, 0, stream);
    }
    final_fc<<<32, 64, 0, stream>>>(h1last, Wfc, bfc, out);
}

// Round 7
// 11140.765 us; speedup vs baseline: 1.2463x; 1.2463x over previous
//
#include <hip/hip_runtime.h>

// ---------------------------------------------------------------------------
// GRU forecaster: B=32, T=2048, I=256, H=512, L=2, O=64   (f16 datapath)
// BOTH LAYERS CONCURRENT in one cooperative scan (layer-1 runs ~1 exchange
// behind layer-0). 8 mega-clusters x 4 batches; grid = 8 x 24 = 192 WGs.
//  - A-WGs (role 0..7): layer-0 member m, j in [64m,+64); wave w owns k-chunk
//    [64w,+64); Wh0 chunk in VGPRs, shared by the 4 batches. Per step: ONE
//    PAIRED poll (4 batches in flight) of h0[t-1] -> dots x4 -> deposit+flag;
//    wave q finalizes batch q and publishes h0[t] into a DEPTH-4 ring.
//  - B-WGs (role 8..23): layer-1 member mB, j in [32mB,+32); wave w owns
//    k-chunk [64w,+64) of Wh1 AND Wi1. Per step: ONE COMBINED paired poll of
//    h1[t-1] x4 AND h0[t] x4 (8 loads in flight; only h0[t] is actually
//    late) -> hh-dots x4 -> xi-dots x4 + flag; wave q finalizes batch q,
//    publishes h1 (parity-2 mailbox).
//  - FLOW CONTROL (proven in round 6): Prog1[b][16] (B-member stores t after
//    publishing h1[t] => consumed h0[t]); ProgA[b][8] (A-member stores t
//    after publishing h0[t] => consumed h0[t-1]). A publishes h0[t] over
//    slot (t&3) (holds h0[t-4]) only when ALL ProgA >= t-3 and ALL
//    Prog1 >= t-4 (one preloaded word per lane, lanes 0..23, __all).
// h0seq + layer-1 GEMM + Wi1 transpose are deleted (xi1 computed in-scan).
// ---------------------------------------------------------------------------

typedef unsigned int  u32;
typedef unsigned short u16;
typedef float v4f __attribute__((ext_vector_type(4)));
typedef _Float16 v2h __attribute__((ext_vector_type(2)));
typedef _Float16 v8h __attribute__((ext_vector_type(8)));

#if defined(__has_builtin)
#  if __has_builtin(__builtin_amdgcn_fdot2)
#    define FDOT2(a, b, c) __builtin_amdgcn_fdot2((a), (b), (c), false)
#  endif
#endif
#ifndef FDOT2
#  define FDOT2(a, b, c) ((c) + (float)(a)[0] * (float)(b)[0] + (float)(a)[1] * (float)(b)[1])
#endif

__device__ __forceinline__ u16 f2h(float f) {
    _Float16 h = (_Float16)f;
    return *(u16*)&h;
}
__device__ __forceinline__ float h2f(u16 b) {
    _Float16 h = *(_Float16*)&b;
    return (float)h;
}
__device__ __forceinline__ u32 LDG(const u32* p) {
    return __hip_atomic_load(p, __ATOMIC_RELAXED, __HIP_MEMORY_SCOPE_AGENT);
}

// --------------------------- prep kernels ----------------------------------

// src fp32 [R][C] -> dst f16 [C][R]  (32x32 tiles)
__global__ __launch_bounds__(256) void transpose_cast(const float* __restrict__ src,
                                                      u16* __restrict__ dst,
                                                      int R, int C) {
    __shared__ u16 tile[32][33];
    int c0 = blockIdx.x * 32, r0 = blockIdx.y * 32;
    int t = threadIdx.x;
    {
        int rl = t >> 3, cl4 = (t & 7) * 4;
        float4 v = *(const float4*)&src[(size_t)(r0 + rl) * C + c0 + cl4];
        tile[rl][cl4 + 0] = f2h(v.x);
        tile[rl][cl4 + 1] = f2h(v.y);
        tile[rl][cl4 + 2] = f2h(v.z);
        tile[rl][cl4 + 3] = f2h(v.w);
    }
    __syncthreads();
    {
        int cl = t >> 3, rl4 = (t & 7) * 4;
        uint2 o;
        o.x = (u32)tile[rl4 + 0][cl] | ((u32)tile[rl4 + 1][cl] << 16);
        o.y = (u32)tile[rl4 + 2][cl] | ((u32)tile[rl4 + 3][cl] << 16);
        *(uint2*)&dst[(size_t)(c0 + cl) * R + r0 + rl4] = o;
    }
}

// Layer-0 pack (8 members, j64): uint4 index ((m*8+w)*24 + c)*64 + l,
// c = g*8+qk: holds k-pairs kb = w*64+qk*8, col = g*512 + m*64 + l.
__global__ __launch_bounds__(256) void pack_wh(const float* __restrict__ Wh,
                                               uint4* __restrict__ dst) {
    int id = blockIdx.x * 256 + threadIdx.x;   // < 98304
    int l = id & 63;
    int c = (id >> 6) % 24;
    int mw = id / 1536;                        // m*8 + w
    int m = mw >> 3, w = mw & 7;
    int g = c >> 3, qk = c & 7;
    int col = g * 512 + m * 64 + l;
    int kb = w * 64 + qk * 8;
    u32 d[4];
#pragma unroll
    for (int p = 0; p < 4; ++p) {
        u16 a = f2h(Wh[(size_t)(kb + 2 * p) * 1536 + col]);
        u16 b = f2h(Wh[(size_t)(kb + 2 * p + 1) * 1536 + col]);
        d[p] = (u32)a | ((u32)b << 16);
    }
    uint4 o; o.x = d[0]; o.y = d[1]; o.z = d[2]; o.w = d[3];
    dst[id] = o;
}

// Layer-1 pack (16 members, j32, lane khalf split): uint4 index
// ((mB*8+w)*12 + c)*64 + l, c = g*4+qk4: holds k-pairs
// kb = w*64 + (l>>5)*32 + qk4*8, col = g*512 + mB*32 + (l&31).
__global__ __launch_bounds__(256) void pack_whB(const float* __restrict__ Wh,
                                                uint4* __restrict__ dst) {
    int id = blockIdx.x * 256 + threadIdx.x;   // < 98304
    int l = id & 63;
    int c = (id >> 6) % 12;
    int mw = id / 768;                         // mB*8 + w
    int mB = mw >> 3, w = mw & 7;
    int g = c >> 2, qk4 = c & 3;
    int col = g * 512 + mB * 32 + (l & 31);
    int kb = w * 64 + (l >> 5) * 32 + qk4 * 8;
    u32 d[4];
#pragma unroll
    for (int p = 0; p < 4; ++p) {
        u16 a = f2h(Wh[(size_t)(kb + 2 * p) * 1536 + col]);
        u16 b = f2h(Wh[(size_t)(kb + 2 * p + 1) * 1536 + col]);
        d[p] = (u32)a | ((u32)b << 16);
    }
    uint4 o; o.x = d[0]; o.y = d[1]; o.z = d[2]; o.w = d[3];
    dst[id] = o;
}

// ---------------- GEMM: xi_chunk = A_rows @ Bt^T + bias -> f16 --------------
template <int K, bool AF32>
__global__ __launch_bounds__(256) void gemm_xi(const void* __restrict__ Ap,
                                               const u16* __restrict__ Bt,
                                               const float* __restrict__ bias,
                                               u16* __restrict__ C,
                                               int t0, int lgTc) {
    __shared__ u16 As[64 * 40];
    __shared__ u16 Bs[64 * 40];
    const int tid = threadIdx.x;
    const int n0 = blockIdx.x * 64;
    const int m0 = blockIdx.y * 64;
    const int row = tid >> 2, koff = (tid & 3) * 8;
    const int lane = tid & 63, w = tid >> 6;
    const int m = m0 + row;
    const int b = m >> lgTc;
    const int tl = m & ((1 << lgTc) - 1);
    const size_t srow = ((size_t)b << 11) + (size_t)(t0 + tl);
    v4f acc[4];
#pragma unroll
    for (int i = 0; i < 4; ++i) acc[i] = (v4f){0.f, 0.f, 0.f, 0.f};

    for (int k0 = 0; k0 < K; k0 += 32) {
        if (AF32) {
            const float* A = (const float*)Ap;
            float4 v0 = *(const float4*)&A[srow * K + k0 + koff];
            float4 v1 = *(const float4*)&A[srow * K + k0 + koff + 4];
            uint4 o;
            o.x = (u32)f2h(v0.x) | ((u32)f2h(v0.y) << 16);
            o.y = (u32)f2h(v0.z) | ((u32)f2h(v0.w) << 16);
            o.z = (u32)f2h(v1.x) | ((u32)f2h(v1.y) << 16);
            o.w = (u32)f2h(v1.z) | ((u32)f2h(v1.w) << 16);
            *(uint4*)&As[row * 40 + koff] = o;
        } else {
            const u16* A = (const u16*)Ap;
            *(uint4*)&As[row * 40 + koff] =
                *(const uint4*)&A[srow * K + k0 + koff];
        }
        *(uint4*)&Bs[row * 40 + koff] =
            *(const uint4*)&Bt[(size_t)(n0 + row) * K + k0 + koff];
        __syncthreads();
        v8h a = *(const v8h*)&As[(w * 16 + (lane & 15)) * 40 + (lane >> 4) * 8];
#pragma unroll
        for (int nt = 0; nt < 4; ++nt) {
            v8h bm = *(const v8h*)&Bs[(nt * 16 + (lane & 15)) * 40 + (lane >> 4) * 8];
            acc[nt] = __builtin_amdgcn_mfma_f32_16x16x32_f16(a, bm, acc[nt], 0, 0, 0);
        }
        __syncthreads();
    }
#pragma unroll
    for (int nt = 0; nt < 4; ++nt) {
        int col = n0 + nt * 16 + (lane & 15);
        float bv = bias[col];
#pragma unroll
        for (int rI = 0; rI < 4; ++rI) {
            int rowm = m0 + w * 16 + (lane >> 4) * 4 + rI;
            C[(size_t)rowm * 1536 + col] = f2h(acc[nt][rI] + bv);
        }
    }
}

// --------------------------- fused 2-layer GRU scan -------------------------
// grid = 192 x 512. mc = wg/24 (0..7, 4 batches), role = wg%24.
__global__ __launch_bounds__(512) void gru_scan2(const u16* __restrict__ xi,
                                                 const uint4* __restrict__ Wh0p,
                                                 const uint4* __restrict__ Wh1B,
                                                 const uint4* __restrict__ Wi1B,
                                                 const float* __restrict__ bi1,
                                                 const float* __restrict__ bhn0,
                                                 const float* __restrict__ bhn1,
                                                 u32* __restrict__ Hb0,
                                                 u32* __restrict__ Hb1,
                                                 u32* __restrict__ ProgA,
                                                 u32* __restrict__ Prog1,
                                                 float* __restrict__ h1last,
                                                 float* __restrict__ hstate0,
                                                 float* __restrict__ hstate1,
                                                 int t0, int Tc) {
    struct SA {
        u16 Sh[4][8][64];            // h0[t-1], per batch per k-chunk (wave-local)
        float P0[2][4][8][3][64];    // [parity][batch][wave][gate][j]
        u32 flag[2][4][8];
    };
    struct SB {
        u16 Sh1[4][8][64];           // h1[t-1]
        u16 Sh0[4][8][64];           // h0[t]
        float P1[2][4][8][6][32];    // [par][batch][wave][hr,hz,hn,xr,xz,xn][j]
        u32 flag[2][4][8];
    };
    union SU { SA a; SB b; };
    __shared__ __align__(16) SU S;

    const int tid = threadIdx.x;
    const int wg = blockIdx.x;
    const int mc = wg / 24;
    const int rr = wg % 24;
    const int W = tid >> 6, lane = tid & 63;
    const int tEnd = t0 + Tc;

    if (rr < 8) {
        // =================== A: layer 0, member m = rr =====================
        const int m = rr;
        if (tid < 64) ((u32*)S.a.flag)[tid] = 0;
        uint4 Wreg[24];
        {
            const uint4* src = Wh0p + ((size_t)(m * 8 + W) * 24) * 64 + lane;
#pragma unroll
            for (int c = 0; c < 24; ++c) Wreg[c] = src[c * 64];
        }
        const int j = m * 64 + lane;
        const int bq = mc * 4 + W;          // valid for W<4
        float bhnv = 0.f, hprev = 0.f;
        u16 rx = 0, rz = 0, rn = 0;
        const u32* gp = ProgA;               // guard pointer (W<4 only)
        u32 pgv = 0;                         // preloaded progress word
        if (W < 4) {
            bhnv = bhn0[j];
            if (t0 > 0) hprev = hstate0[bq * 512 + j];
            const u16* p = xi + ((size_t)bq * Tc) * 1536 + j;
            rx = p[0]; rz = p[512]; rn = p[1024];
            gp = (lane < 8)  ? (ProgA + bq * 8 + lane)
               : (lane < 24) ? (Prog1 + bq * 16 + (lane - 8))
                             : (ProgA + bq * 8);
            pgv = LDG(gp);
        }
        __syncthreads();   // flag init visible before loop

        for (int t = t0; t < tEnd; ++t) {
            const int pp = t & 1;
            // ---- PAIRED poll of h0[t-1], 4 batches in flight --------------
            {
                u32 v0 = 0, v1 = 0, v2 = 0, v3 = 0;
                if (t > 0) {
                    const u32 tg = (u32)(u16)t << 16;
                    const u32* bp = Hb0 + (size_t)(mc * 4) * 2048 +
                                    ((t - 1) & 3) * 512 + W * 64 + lane;
                    for (int it = 0; it < 2000000; ++it) {
                        v0 = LDG(bp);
                        v1 = LDG(bp + 2048);
                        v2 = LDG(bp + 4096);
                        v3 = LDG(bp + 6144);
                        u32 bad = (((v0 ^ tg) | (v1 ^ tg) | (v2 ^ tg) | (v3 ^ tg))
                                   & 0xFFFF0000u);
                        if (!bad) break;
                        if (it > 6) __builtin_amdgcn_s_sleep(2);
                    }
                }
                S.a.Sh[0][W][lane] = (u16)v0;
                S.a.Sh[1][W][lane] = (u16)v1;
                S.a.Sh[2][W][lane] = (u16)v2;
                S.a.Sh[3][W][lane] = (u16)v3;
            }
            // ---- dots x4, deposit+flag; wave q finalizes batch q ----------
#pragma unroll
            for (int q = 0; q < 4; ++q) {
                float a0 = 0.f, a1 = 0.f, a2 = 0.f;
#pragma unroll
                for (int qk = 0; qk < 8; ++qk) {
                    v8h h8 = *(const v8h*)&S.a.Sh[q][W][qk * 8];
                    const v2h* hp = (const v2h*)&h8;
                    const v2h* p0 = (const v2h*)&Wreg[qk];
                    const v2h* p1 = (const v2h*)&Wreg[8 + qk];
                    const v2h* p2 = (const v2h*)&Wreg[16 + qk];
#pragma unroll
                    for (int p = 0; p < 4; ++p) {
                        a0 = FDOT2(p0[p], hp[p], a0);
                        a1 = FDOT2(p1[p], hp[p], a1);
                        a2 = FDOT2(p2[p], hp[p], a2);
                    }
                }
                S.a.P0[pp][q][W][0][lane] = a0;
                S.a.P0[pp][q][W][1][lane] = a1;
                S.a.P0[pp][q][W][2][lane] = a2;
                if (lane == 0)
                    __hip_atomic_store(&S.a.flag[pp][q][W], (u32)(t + 1),
                                       __ATOMIC_RELEASE, __HIP_MEMORY_SCOPE_WORKGROUP);
                if (W == q) {
                    for (int it = 0; it < 2000000; ++it) {
                        u32 fv = __hip_atomic_load(&S.a.flag[pp][q][lane & 7],
                                                   __ATOMIC_ACQUIRE, __HIP_MEMORY_SCOPE_WORKGROUP);
                        if (__all((lane >= 8) | (fv == (u32)(t + 1)))) break;
                        if (it > 16) __builtin_amdgcn_s_sleep(1);
                    }
                    float s0 = 0.f, s1 = 0.f, s2 = 0.f;
#pragma unroll
                    for (int w2 = 0; w2 < 8; ++w2) {
                        s0 += S.a.P0[pp][q][w2][0][lane];
                        s1 += S.a.P0[pp][q][w2][1][lane];
                        s2 += S.a.P0[pp][q][w2][2][lane];
                    }
                    float r = 1.f / (1.f + __expf(-(h2f(rx) + s0)));
                    float z = 1.f / (1.f + __expf(-(h2f(rz) + s1)));
                    float nx = h2f(rn) + r * (s2 + bhnv);
                    float n = 1.f - 2.f / (__expf(2.f * nx) + 1.f);   // tanh
                    float hn = (1.f - z) * n + z * hprev;
                    hprev = hn;
                    // ---- ring guard: ALL consumers done with h0[t-4] ----
                    if (t >= 4) {
                        const int thr = (lane < 8) ? (t - 3) : (t - 4);
                        if (!__all((lane >= 24) || ((int)pgv >= thr))) {
                            for (int it = 0; it < 2000000; ++it) {
                                pgv = LDG(gp);
                                if (__all((lane >= 24) || ((int)pgv >= thr))) break;
                                if (it > 8) __builtin_amdgcn_s_sleep(1);
                            }
                        }
                    }
                    __hip_atomic_store(Hb0 + (size_t)bq * 2048 + (t & 3) * 512 + j,
                                       ((u32)(u16)(t + 1) << 16) | (u32)f2h(hn),
                                       __ATOMIC_RELAXED, __HIP_MEMORY_SCOPE_AGENT);
                    if (lane == 0)
                        __hip_atomic_store(ProgA + bq * 8 + m, (u32)t,
                                           __ATOMIC_RELAXED, __HIP_MEMORY_SCOPE_AGENT);
                    pgv = LDG(gp);          // preload for next step (hidden)
                    if (t + 1 < tEnd) {     // prefetch xi for t+1
                        const u16* p = xi + ((size_t)bq * Tc + (t + 1 - t0)) * 1536 + j;
                        rx = p[0]; rz = p[512]; rn = p[1024];
                    }
                }
            }
        }
        if (W < 4) hstate0[bq * 512 + j] = hprev;
    } else {
        // =================== B: layer 1, member mB = rr-8 ==================
        const int mB = rr - 8;
        if (tid < 64) ((u32*)S.b.flag)[tid] = 0;
        uint4 Hreg[12], Xreg[12];
        {
            const uint4* hs = Wh1B + ((size_t)(mB * 8 + W) * 12) * 64 + lane;
            const uint4* xs = Wi1B + ((size_t)(mB * 8 + W) * 12) * 64 + lane;
#pragma unroll
            for (int c = 0; c < 12; ++c) { Hreg[c] = hs[c * 64]; Xreg[c] = xs[c * 64]; }
        }
        const int jB = mB * 32 + (lane & 31);
        const int kloc = (lane >> 5) * 32;
        const float b_r = bi1[jB], b_z = bi1[512 + jB], b_n = bi1[1024 + jB];
        const float bh = bhn1[jB];
        const int bq = mc * 4 + W;          // valid for W<4
        float hprev = 0.f;
        if (W < 4 && t0 > 0) hprev = hstate1[bq * 512 + jB];
        __syncthreads();

        for (int t = t0; t < tEnd; ++t) {
            const int pp = t & 1;
            // ---- COMBINED paired poll: h1[t-1] x4 AND h0[t] x4 ------------
            {
                u32 r0 = 0, r1 = 0, r2 = 0, r3 = 0;
                u32 s0 = 0, s1 = 0, s2 = 0, s3 = 0;
                const u32 tg0 = (u32)(u16)(t + 1) << 16;
                const u32* p0 = Hb0 + (size_t)(mc * 4) * 2048 +
                                (t & 3) * 512 + W * 64 + lane;
                if (t > 0) {
                    const u32 tg1 = (u32)(u16)t << 16;
                    const u32* p1 = Hb1 + (size_t)(mc * 4) * 1024 +
                                    ((t - 1) & 1) * 512 + W * 64 + lane;
                    for (int it = 0; it < 2000000; ++it) {
                        r0 = LDG(p1);
                        r1 = LDG(p1 + 1024);
                        r2 = LDG(p1 + 2048);
                        r3 = LDG(p1 + 3072);
                        s0 = LDG(p0);
                        s1 = LDG(p0 + 2048);
                        s2 = LDG(p0 + 4096);
                        s3 = LDG(p0 + 6144);
                        u32 bad = (((r0 ^ tg1) | (r1 ^ tg1) | (r2 ^ tg1) | (r3 ^ tg1) |
                                    (s0 ^ tg0) | (s1 ^ tg0) | (s2 ^ tg0) | (s3 ^ tg0))
                                   & 0xFFFF0000u);
                        if (!bad) break;
                        if (it > 6) __builtin_amdgcn_s_sleep(2);
                    }
                } else {
                    for (int it = 0; it < 2000000; ++it) {
                        s0 = LDG(p0);
                        s1 = LDG(p0 + 2048);
                        s2 = LDG(p0 + 4096);
                        s3 = LDG(p0 + 6144);
                        u32 bad = (((s0 ^ tg0) | (s1 ^ tg0) | (s2 ^ tg0) | (s3 ^ tg0))
                                   & 0xFFFF0000u);
                        if (!bad) break;
                        if (it > 6) __builtin_amdgcn_s_sleep(2);
                    }
                }
                S.b.Sh1[0][W][lane] = (u16)r0;
                S.b.Sh1[1][W][lane] = (u16)r1;
                S.b.Sh1[2][W][lane] = (u16)r2;
                S.b.Sh1[3][W][lane] = (u16)r3;
                S.b.Sh0[0][W][lane] = (u16)s0;
                S.b.Sh0[1][W][lane] = (u16)s1;
                S.b.Sh0[2][W][lane] = (u16)s2;
                S.b.Sh0[3][W][lane] = (u16)s3;
            }
            // ---- hh dots x4 (h1[t-1]) -------------------------------------
#pragma unroll
            for (int q = 0; q < 4; ++q) {
                float a0 = 0.f, a1 = 0.f, a2 = 0.f;
#pragma unroll
                for (int qk = 0; qk < 4; ++qk) {
                    v8h h8 = *(const v8h*)&S.b.Sh1[q][W][kloc + qk * 8];
                    const v2h* hp = (const v2h*)&h8;
                    const v2h* p0 = (const v2h*)&Hreg[qk];
                    const v2h* p1 = (const v2h*)&Hreg[4 + qk];
                    const v2h* p2 = (const v2h*)&Hreg[8 + qk];
#pragma unroll
                    for (int p = 0; p < 4; ++p) {
                        a0 = FDOT2(p0[p], hp[p], a0);
                        a1 = FDOT2(p1[p], hp[p], a1);
                        a2 = FDOT2(p2[p], hp[p], a2);
                    }
                }
                a0 += __shfl_xor(a0, 32);
                a1 += __shfl_xor(a1, 32);
                a2 += __shfl_xor(a2, 32);
                if (lane < 32) {
                    S.b.P1[pp][q][W][0][lane] = a0;
                    S.b.P1[pp][q][W][1][lane] = a1;
                    S.b.P1[pp][q][W][2][lane] = a2;
                }
            }
            // ---- xi dots x4 (h0[t]) + flag; wave q finalizes batch q ------
#pragma unroll
            for (int q = 0; q < 4; ++q) {
                float a0 = 0.f, a1 = 0.f, a2 = 0.f;
#pragma unroll
                for (int qk = 0; qk < 4; ++qk) {
                    v8h h8 = *(const v8h*)&S.b.Sh0[q][W][kloc + qk * 8];
                    const v2h* hp = (const v2h*)&h8;
                    const v2h* p0 = (const v2h*)&Xreg[qk];
                    const v2h* p1 = (const v2h*)&Xreg[4 + qk];
                    const v2h* p2 = (const v2h*)&Xreg[8 + qk];
#pragma unroll
                    for (int p = 0; p < 4; ++p) {
                        a0 = FDOT2(p0[p], hp[p], a0);
                        a1 = FDOT2(p1[p], hp[p], a1);
                        a2 = FDOT2(p2[p], hp[p], a2);
                    }
                }
                a0 += __shfl_xor(a0, 32);
                a1 += __shfl_xor(a1, 32);
                a2 += __shfl_xor(a2, 32);
                if (lane < 32) {
                    S.b.P1[pp][q][W][3][lane] = a0;
                    S.b.P1[pp][q][W][4][lane] = a1;
                    S.b.P1[pp][q][W][5][lane] = a2;
                }
                if (lane == 0)
                    __hip_atomic_store(&S.b.flag[pp][q][W], (u32)(t + 1),
                                       __ATOMIC_RELEASE, __HIP_MEMORY_SCOPE_WORKGROUP);
                if (W == q) {
                    for (int it = 0; it < 2000000; ++it) {
                        u32 fv = __hip_atomic_load(&S.b.flag[pp][q][lane & 7],
                                                   __ATOMIC_ACQUIRE, __HIP_MEMORY_SCOPE_WORKGROUP);
                        if (__all((lane >= 8) | (fv == (u32)(t + 1)))) break;
                        if (it > 16) __builtin_amdgcn_s_sleep(1);
                    }
                    const int lj = lane & 31;
                    float HR = 0.f, HZ = 0.f, HN = 0.f, XR = 0.f, XZ = 0.f, XN = 0.f;
#pragma unroll
                    for (int w2 = 0; w2 < 8; ++w2) {
                        HR += S.b.P1[pp][q][w2][0][lj];
                        HZ += S.b.P1[pp][q][w2][1][lj];
                        HN += S.b.P1[pp][q][w2][2][lj];
                        XR += S.b.P1[pp][q][w2][3][lj];
                        XZ += S.b.P1[pp][q][w2][4][lj];
                        XN += S.b.P1[pp][q][w2][5][lj];
                    }
                    if (lane < 32) {
                        float r = 1.f / (1.f + __expf(-(XR + b_r + HR)));
                        float z = 1.f / (1.f + __expf(-(XZ + b_z + HZ)));
                        float nx = XN + b_n + r * (HN + bh);
                        float n = 1.f - 2.f / (__expf(2.f * nx) + 1.f);   // tanh
                        float hn = (1.f - z) * n + z * hprev;
                        hprev = hn;
                        __hip_atomic_store(Hb1 + (size_t)bq * 1024 + (t & 1) * 512 + jB,
                                           ((u32)(u16)(t + 1) << 16) | (u32)f2h(hn),
                                           __ATOMIC_RELAXED, __HIP_MEMORY_SCOPE_AGENT);
                        if (t == 2047) h1last[bq * 512 + jB] = hn;
                    }
                    if (lane == 0)
                        __hip_atomic_store(Prog1 + bq * 16 + mB, (u32)t,
                                           __ATOMIC_RELAXED, __HIP_MEMORY_SCOPE_AGENT);
                }
            }
        }
        if (W < 4 && lane < 32) hstate1[bq * 512 + jB] = hprev;
    }
}

// --------------------------- final FC --------------------------------------
__global__ __launch_bounds__(64) void final_fc(const float* __restrict__ h1,
                                               const float* __restrict__ Wfc,
                                               const float* __restrict__ bfc,
                                               float* __restrict__ out) {
    int b = blockIdx.x, o = threadIdx.x;
    float acc = bfc[o];
    for (int k = 0; k < 512; ++k) acc += h1[b * 512 + k] * Wfc[k * 64 + o];
    out[b * 64 + o] = acc;
}

// --------------------------- launch ----------------------------------------

extern "C" void kernel_launch(void* const* d_in, const int* in_sizes, int n_in,
                              void* d_out, int out_size, void* d_ws, size_t ws_size,
                              hipStream_t stream) {
    const float* x    = (const float*)d_in[0];
    const float* Wi0  = (const float*)d_in[1];
    const float* bi0  = (const float*)d_in[2];
    const float* Wh0  = (const float*)d_in[3];
    const float* bhn0 = (const float*)d_in[4];
    const float* Wi1  = (const float*)d_in[5];
    const float* bi1  = (const float*)d_in[6];
    const float* Wh1  = (const float*)d_in[7];
    const float* bhn1 = (const float*)d_in[8];
    const float* Wfc  = (const float*)d_in[9];
    const float* bfc  = (const float*)d_in[10];
    float* out = (float*)d_out;
    (void)in_sizes; (void)n_in; (void)out_size;

    char* ws = (char*)d_ws;
    size_t off = 0;
    auto take = [&](size_t bytes) -> char* {
        char* p = ws + off;
        off = (off + bytes + 255) & ~(size_t)255;
        return p;
    };
    u16*  Wi0t  = (u16*)take(1536 * 256 * 2);
    uint4* Wh0p = (uint4*)take(98304 * 16);
    uint4* Wh1B = (uint4*)take(98304 * 16);
    uint4* Wi1B = (uint4*)take(98304 * 16);
    u32*  Hb0   = (u32*)take(32 * 2048 * 4);    // depth-4 ring
    u32*  Hb1   = (u32*)take(32 * 1024 * 4);    // parity-2
    u32*  ProgA = (u32*)take(32 * 8 * 4);
    u32*  Prog1 = (u32*)take(32 * 16 * 4);
    float* hstate0 = (float*)take(32 * 512 * 4);
    float* hstate1 = (float*)take(32 * 512 * 4);
    float* h1last  = (float*)take(32 * 512 * 4);
    size_t fixed_end = off;

    int Tc = 2048;
    if (ws_size > 0) {
        while (Tc > 128 &&
               fixed_end + (size_t)32 * Tc * 1536 * 2 > ws_size) Tc >>= 1;
    }
    int lgTc = 31 - __builtin_clz((u32)Tc);
    u16* xibuf = (u16*)take((size_t)32 * Tc * 1536 * 2);
    int nChunk = 2048 / Tc;

    // zero mailboxes + progress (tags absolute; fresh per launch/replay)
    hipMemsetAsync(Hb0, 0, 32 * 2048 * 4, stream);
    hipMemsetAsync(Hb1, 0, 32 * 1024 * 4, stream);
    hipMemsetAsync(ProgA, 0, 32 * 8 * 4, stream);
    hipMemsetAsync(Prog1, 0, 32 * 16 * 4, stream);

    // prep
    transpose_cast<<<dim3(48, 8), 256, 0, stream>>>(Wi0, Wi0t, 256, 1536);
    pack_wh<<<384, 256, 0, stream>>>(Wh0, Wh0p);
    pack_whB<<<384, 256, 0, stream>>>(Wh1, Wh1B);
    pack_whB<<<384, 256, 0, stream>>>(Wi1, Wi1B);

    for (int c = 0; c < nChunk; ++c) {
        int t0 = c * Tc;
        gemm_xi<256, true><<<dim3(24, Tc / 2), 256, 0, stream>>>(
            (const void*)x, Wi0t, bi0, xibuf, t0, lgTc);
        const u16* xi_p = xibuf;
        const uint4* wh0_p = Wh0p; const uint4* wh1_p = Wh1B; const uint4* wi1_p = Wi1B;
        const float* bi1_p = bi1; const float* bh0_p = bhn0; const float* bh1_p = bhn1;
        u32* hb0_p = Hb0; u32* hb1_p = Hb1; u32* pga_p = ProgA; u32* pg1_p = Prog1;
        float* h1l_p = h1last; float* st0_p = hstate0; float* st1_p = hstate1;
        int t0v = t0, Tcv = Tc;
        void* args[] = {&xi_p, &wh0_p, &wh1_p, &wi1_p, &bi1_p, &bh0_p, &bh1_p,
                        &hb0_p, &hb1_p, &pga_p, &pg1_p, &h1l_p, &st0_p, &st1_p,
                        &t0v, &Tcv};
        hipLaunchCooperativeKernel(gru_scan2, dim3(192), dim3(512), args, 0, stream);
    }
    final_fc<<<32, 64, 0, stream>>>(h1last, Wfc, bfc, out);
}

// Round 8
// 7387.112 us; speedup vs baseline: 1.8796x; 1.5081x over previous
//
#include <hip/hip_runtime.h>

// ---------------------------------------------------------------------------
// GRU forecaster: B=32, T=2048, I=256, H=512, L=2, O=64   (f16 datapath)
// Scan: 32 clusters (1 batch each) x 8 member WGs, 512 threads (8 waves).
// Member m owns output j in [64m, 64m+64). Wave w owns k-chunk [64w,+64)
// == member w's h output, so wave w polls ONLY member w's mailbox.
// Wave 0 is compute + finalizer: its own partial stays in registers; waves
// 1-7 deposit partials in LDS with release-flags; wave 0 sums, activates,
// publishes h as u32 {epoch<<16|f16} agent-scope atomics, prefetches xi.
// POLL FAST PATH: all members of a cluster share an XCD (wg%8 residue), so
// consumers poll with sc0 (L2-scope) loads 3 of 4 iterations (~200cy RTT
// when the agent store left the line L2-serviceable) and an agent-scope
// load every 4th iteration as the cross-XCD-safe fallback (tag check
// rejects stale; fallback guarantees progress). Producer store unchanged.
// ---------------------------------------------------------------------------

typedef unsigned int  u32;
typedef unsigned short u16;
typedef float v4f __attribute__((ext_vector_type(4)));
typedef _Float16 v2h __attribute__((ext_vector_type(2)));
typedef _Float16 v8h __attribute__((ext_vector_type(8)));

#if defined(__has_builtin)
#  if __has_builtin(__builtin_amdgcn_fdot2)
#    define FDOT2(a, b, c) __builtin_amdgcn_fdot2((a), (b), (c), false)
#  endif
#endif
#ifndef FDOT2
#  define FDOT2(a, b, c) ((c) + (float)(a)[0] * (float)(b)[0] + (float)(a)[1] * (float)(b)[1])
#endif

__device__ __forceinline__ u16 f2h(float f) {
    _Float16 h = (_Float16)f;
    return *(u16*)&h;
}
__device__ __forceinline__ float h2f(u16 b) {
    _Float16 h = *(_Float16*)&b;
    return (float)h;
}

// L1-bypassing, L2-scoped load (fast same-XCD mailbox read).
__device__ __forceinline__ u32 load_sc0(const u32* p) {
    u32 v;
    asm volatile("global_load_dword %0, %1, off sc0\n\t"
                 "s_waitcnt vmcnt(0)"
                 : "=v"(v) : "v"(p) : "memory");
    return v;
}

// --------------------------- prep kernels ----------------------------------

// src fp32 [R][C] -> dst f16 [C][R]  (32x32 tiles)
__global__ __launch_bounds__(256) void transpose_cast(const float* __restrict__ src,
                                                      u16* __restrict__ dst,
                                                      int R, int C) {
    __shared__ u16 tile[32][33];
    int c0 = blockIdx.x * 32, r0 = blockIdx.y * 32;
    int t = threadIdx.x;
    {
        int rl = t >> 3, cl4 = (t & 7) * 4;
        float4 v = *(const float4*)&src[(size_t)(r0 + rl) * C + c0 + cl4];
        tile[rl][cl4 + 0] = f2h(v.x);
        tile[rl][cl4 + 1] = f2h(v.y);
        tile[rl][cl4 + 2] = f2h(v.z);
        tile[rl][cl4 + 3] = f2h(v.w);
    }
    __syncthreads();
    {
        int cl = t >> 3, rl4 = (t & 7) * 4;
        uint2 o;
        o.x = (u32)tile[rl4 + 0][cl] | ((u32)tile[rl4 + 1][cl] << 16);
        o.y = (u32)tile[rl4 + 2][cl] | ((u32)tile[rl4 + 3][cl] << 16);
        *(uint2*)&dst[(size_t)(c0 + cl) * R + r0 + rl4] = o;
    }
}

// Wh fp32 [512][1536] -> f16 packed for the scan. uint4 index
// ((m*8 + w)*24 + c)*64 + l,  c = g*8+qk. Holds k-pairs
// {Wh[kb+2p][col], Wh[kb+2p+1][col]}, kb = w*64 + qk*8, col = g*512 + m*64 + l.
__global__ __launch_bounds__(256) void pack_wh(const float* __restrict__ Wh,
                                               uint4* __restrict__ dst) {
    int id = blockIdx.x * 256 + threadIdx.x;   // < 98304
    int l = id & 63;
    int c = (id >> 6) % 24;
    int mw = id / 1536;                        // m*8 + w
    int m = mw >> 3, w = mw & 7;
    int g = c >> 3, qk = c & 7;
    int col = g * 512 + m * 64 + l;
    int kb = w * 64 + qk * 8;
    u32 d[4];
#pragma unroll
    for (int p = 0; p < 4; ++p) {
        u16 a = f2h(Wh[(size_t)(kb + 2 * p) * 1536 + col]);
        u16 b = f2h(Wh[(size_t)(kb + 2 * p + 1) * 1536 + col]);
        d[p] = (u32)a | ((u32)b << 16);
    }
    uint4 o; o.x = d[0]; o.y = d[1]; o.z = d[2]; o.w = d[3];
    dst[id] = o;
}

// ---------------- GEMM: xi_chunk = A_rows @ Bt^T + bias -> f16 --------------
template <int K, bool AF32>
__global__ __launch_bounds__(256) void gemm_xi(const void* __restrict__ Ap,
                                               const u16* __restrict__ Bt,
                                               const float* __restrict__ bias,
                                               u16* __restrict__ C,
                                               int t0, int lgTc) {
    __shared__ u16 As[64 * 40];
    __shared__ u16 Bs[64 * 40];
    const int tid = threadIdx.x;
    const int n0 = blockIdx.x * 64;
    const int m0 = blockIdx.y * 64;
    const int row = tid >> 2, koff = (tid & 3) * 8;
    const int lane = tid & 63, w = tid >> 6;
    const int m = m0 + row;
    const int b = m >> lgTc;
    const int tl = m & ((1 << lgTc) - 1);
    const size_t srow = ((size_t)b << 11) + (size_t)(t0 + tl);
    v4f acc[4];
#pragma unroll
    for (int i = 0; i < 4; ++i) acc[i] = (v4f){0.f, 0.f, 0.f, 0.f};

    for (int k0 = 0; k0 < K; k0 += 32) {
        if (AF32) {
            const float* A = (const float*)Ap;
            float4 v0 = *(const float4*)&A[srow * K + k0 + koff];
            float4 v1 = *(const float4*)&A[srow * K + k0 + koff + 4];
            uint4 o;
            o.x = (u32)f2h(v0.x) | ((u32)f2h(v0.y) << 16);
            o.y = (u32)f2h(v0.z) | ((u32)f2h(v0.w) << 16);
            o.z = (u32)f2h(v1.x) | ((u32)f2h(v1.y) << 16);
            o.w = (u32)f2h(v1.z) | ((u32)f2h(v1.w) << 16);
            *(uint4*)&As[row * 40 + koff] = o;
        } else {
            const u16* A = (const u16*)Ap;
            *(uint4*)&As[row * 40 + koff] =
                *(const uint4*)&A[srow * K + k0 + koff];
        }
        *(uint4*)&Bs[row * 40 + koff] =
            *(const uint4*)&Bt[(size_t)(n0 + row) * K + k0 + koff];
        __syncthreads();
        v8h a = *(const v8h*)&As[(w * 16 + (lane & 15)) * 40 + (lane >> 4) * 8];
#pragma unroll
        for (int nt = 0; nt < 4; ++nt) {
            v8h bm = *(const v8h*)&Bs[(nt * 16 + (lane & 15)) * 40 + (lane >> 4) * 8];
            acc[nt] = __builtin_amdgcn_mfma_f32_16x16x32_f16(a, bm, acc[nt], 0, 0, 0);
        }
        __syncthreads();
    }
#pragma unroll
    for (int nt = 0; nt < 4; ++nt) {
        int col = n0 + nt * 16 + (lane & 15);
        float bv = bias[col];
#pragma unroll
        for (int rI = 0; rI < 4; ++rI) {
            int rowm = m0 + w * 16 + (lane >> 4) * 4 + rI;
            C[(size_t)rowm * 1536 + col] = f2h(acc[nt][rI] + bv);
        }
    }
}

// --------------------------- GRU scan (cooperative) -------------------------
// grid = 256 x 512. cluster = wg & 31 (batch), member = wg >> 5 (same XCD).
__global__ __launch_bounds__(512) void gru_scan(const u16* __restrict__ xi,
                                                const uint4* __restrict__ Whp,
                                                const float* __restrict__ bhn,
                                                u32* __restrict__ Hb,
                                                u16* __restrict__ hseq,
                                                float* __restrict__ h1last,
                                                float* __restrict__ hstate,
                                                int t0, int Tc, int layer0) {
    __shared__ __align__(16) u16 Sh[8][64];        // per-wave h-chunk broadcast
    __shared__ float P[2][8][3][64];               // [parity][wave][gate][j-lane]
    __shared__ u32 flagP[2][8];

    const int tid = threadIdx.x;
    const int wg = blockIdx.x;
    const int cluster = wg & 31;          // batch
    const int member = wg >> 5;           // 8 members per cluster, same XCD
    const int W = tid >> 6, lane = tid & 63;
    const int bg = cluster;

    if (tid < 16) ((u32*)flagP)[tid] = 0;

    // weights -> VGPRs (coalesced: per c, 64 lanes read 1KB contiguous)
    uint4 Wreg[24];
    {
        const uint4* src = Whp + ((size_t)(member * 8 + W) * 24) * 64 + lane;
#pragma unroll
        for (int c = 0; c < 24; ++c) Wreg[c] = src[c * 64];
    }

    // wave-0 (finalizer) state: j = member*64 + lane
    const int j = member * 64 + lane;
    float bhnv = 0.f, hprev = 0.f;
    u16 rx = 0, rz = 0, rn = 0;
    if (W == 0) {
        bhnv = bhn[j];
        if (t0 > 0) hprev = hstate[bg * 512 + j];
        const u16* p = xi + (size_t)bg * Tc * 1536 + j;
        rx = p[0]; rz = p[512]; rn = p[1024];
    }
    __syncthreads();   // flag init + weights visible before loop

    u32* pollbase = Hb + (size_t)cluster * 1024 + W * 64 + lane;  // chunk W
    u32* slotj    = Hb + (size_t)cluster * 1024 + j;              // publish
    const bool self0 = (member == 0) && (W == 0);  // own chunk == own output
    u16 hh_keep = 0;

    for (int t = t0; t < t0 + Tc; ++t) {
        const int pp = t & 1;
        // ---- obtain h[t-1] chunk W ----
        u16 hv = 0;
        if (t > 0) {
            if (self0 && t > t0) {
                hv = hh_keep;                       // register path, no global RT
            } else {
                u32* myq = pollbase + ((t - 1) & 1) * 512;
                const u32 target = (u32)(u16)t << 16;
                u32 qv = 0;
                for (int it = 0; it < 4000000; ++it) {
                    if ((it & 3) == 3)
                        qv = __hip_atomic_load(myq, __ATOMIC_RELAXED,
                                               __HIP_MEMORY_SCOPE_AGENT);
                    else
                        qv = load_sc0(myq);         // fast same-XCD L2 path
                    if ((qv & 0xFFFF0000u) == target) break;
                    if (it > 8) __builtin_amdgcn_s_sleep(1);
                }
                hv = (u16)qv;
            }
        }
        Sh[W][lane] = hv;   // within-wave share (lgkmcnt orders write->read)

        // ---- dots over k-chunk W for all 64 j of this member ----
        float a0 = 0.f, a1 = 0.f, a2 = 0.f;
#pragma unroll
        for (int qk = 0; qk < 8; ++qk) {
            v8h h8 = *(const v8h*)&Sh[W][qk * 8];
            const v2h* hp = (const v2h*)&h8;
            v8h w0 = *(const v8h*)&Wreg[qk];
            v8h w1 = *(const v8h*)&Wreg[8 + qk];
            v8h w2 = *(const v8h*)&Wreg[16 + qk];
            const v2h* p0 = (const v2h*)&w0;
            const v2h* p1 = (const v2h*)&w1;
            const v2h* p2 = (const v2h*)&w2;
#pragma unroll
            for (int p = 0; p < 4; ++p) {
                a0 = FDOT2(p0[p], hp[p], a0);
                a1 = FDOT2(p1[p], hp[p], a1);
                a2 = FDOT2(p2[p], hp[p], a2);
            }
        }

        if (W != 0) {
            // deposit partial + release flag; then loop to next step
            P[pp][W][0][lane] = a0;
            P[pp][W][1][lane] = a1;
            P[pp][W][2][lane] = a2;
            if (lane == 0)
                __hip_atomic_store(&flagP[pp][W], (u32)(t + 1), __ATOMIC_RELEASE,
                                   __HIP_MEMORY_SCOPE_WORKGROUP);
        } else {
            // ---- finalize on wave 0 (own partial in regs) ----
            for (int it = 0; it < 4000000; ++it) {
                u32 v = __hip_atomic_load(&flagP[pp][lane & 7], __ATOMIC_ACQUIRE,
                                          __HIP_MEMORY_SCOPE_WORKGROUP);
                bool ok = ((lane & 7) == 0) || (v == (u32)(t + 1));
                if (__all(ok)) break;
                if (it > 32) __builtin_amdgcn_s_sleep(1);
            }
#pragma unroll
            for (int w = 1; w < 8; ++w) {
                a0 += P[pp][w][0][lane];
                a1 += P[pp][w][1][lane];
                a2 += P[pp][w][2][lane];
            }
            float r = 1.f / (1.f + __expf(-(h2f(rx) + a0)));
            float z = 1.f / (1.f + __expf(-(h2f(rz) + a1)));
            float nx = h2f(rn) + r * (a2 + bhnv);
            float n = 1.f - 2.f / (__expf(2.f * nx) + 1.f);   // tanh
            float hn = (1.f - z) * n + z * hprev;
            hprev = hn;
            u16 hh = f2h(hn);
            hh_keep = hh;
            __hip_atomic_store(&slotj[pp * 512], ((u32)(u16)(t + 1) << 16) | (u32)hh,
                               __ATOMIC_RELAXED, __HIP_MEMORY_SCOPE_AGENT);
            if (layer0) hseq[((size_t)bg * 2048 + t) * 512 + j] = hh;
            if (!layer0 && t == 2047) h1last[bg * 512 + j] = hn;
            if (t + 1 < t0 + Tc) {   // prefetch xi for t+1
                const u16* p = xi + ((size_t)bg * Tc + (t + 1 - t0)) * 1536 + j;
                rx = p[0]; rz = p[512]; rn = p[1024];
            }
        }
    }
    if (W == 0) hstate[bg * 512 + j] = hprev;
}

// --------------------------- final FC --------------------------------------
__global__ __launch_bounds__(64) void final_fc(const float* __restrict__ h1,
                                               const float* __restrict__ Wfc,
                                               const float* __restrict__ bfc,
                                               float* __restrict__ out) {
    int b = blockIdx.x, o = threadIdx.x;
    float acc = bfc[o];
    for (int k = 0; k < 512; ++k) acc += h1[b * 512 + k] * Wfc[k * 64 + o];
    out[b * 64 + o] = acc;
}

// --------------------------- launch ----------------------------------------

extern "C" void kernel_launch(void* const* d_in, const int* in_sizes, int n_in,
                              void* d_out, int out_size, void* d_ws, size_t ws_size,
                              hipStream_t stream) {
    const float* x    = (const float*)d_in[0];
    const float* Wi0  = (const float*)d_in[1];
    const float* bi0  = (const float*)d_in[2];
    const float* Wh0  = (const float*)d_in[3];
    const float* bhn0 = (const float*)d_in[4];
    const float* Wi1  = (const float*)d_in[5];
    const float* bi1  = (const float*)d_in[6];
    const float* Wh1  = (const float*)d_in[7];
    const float* bhn1 = (const float*)d_in[8];
    const float* Wfc  = (const float*)d_in[9];
    const float* bfc  = (const float*)d_in[10];
    float* out = (float*)d_out;
    (void)in_sizes; (void)n_in; (void)out_size;

    char* ws = (char*)d_ws;
    size_t off = 0;
    auto take = [&](size_t bytes) -> char* {
        char* p = ws + off;
        off = (off + bytes + 255) & ~(size_t)255;
        return p;
    };
    u16*  Wi0t  = (u16*)take(1536 * 256 * 2);
    u16*  Wi1t  = (u16*)take(1536 * 512 * 2);
    uint4* Wh0p = (uint4*)take(98304 * 16);
    uint4* Wh1p = (uint4*)take(98304 * 16);
    u32*  Hb0   = (u32*)take(32 * 1024 * 4);
    u32*  Hb1   = (u32*)take(32 * 1024 * 4);
    float* hstate = (float*)take(32 * 512 * 4);
    float* h1last = (float*)take(32 * 512 * 4);
    u16*  h0seq = (u16*)take((size_t)32 * 2048 * 512 * 2);
    size_t fixed_end = off;

    int Tc = 2048;
    if (ws_size > 0) {
        while (Tc > 128 &&
               fixed_end + (size_t)32 * Tc * 1536 * 2 > ws_size) Tc >>= 1;
    }
    int lgTc = 31 - __builtin_clz((u32)Tc);
    u16* xibuf = (u16*)take((size_t)32 * Tc * 1536 * 2);
    int nChunk = 2048 / Tc;

    // prep
    transpose_cast<<<dim3(48, 8), 256, 0, stream>>>(Wi0, Wi0t, 256, 1536);
    transpose_cast<<<dim3(48, 16), 256, 0, stream>>>(Wi1, Wi1t, 512, 1536);
    pack_wh<<<384, 256, 0, stream>>>(Wh0, Wh0p);
    pack_wh<<<384, 256, 0, stream>>>(Wh1, Wh1p);

    // layer 0
    for (int c = 0; c < nChunk; ++c) {
        int t0 = c * Tc;
        gemm_xi<256, true><<<dim3(24, Tc / 2), 256, 0, stream>>>(
            (const void*)x, Wi0t, bi0, xibuf, t0, lgTc);
        const u16* xi_p = xibuf; const uint4* wh_p = Wh0p; const float* bh_p = bhn0;
        u32* hb_p = Hb0; u16* hs_p = h0seq; float* h1_p = nullptr;
        float* st_p = hstate; int t0v = t0, Tcv = Tc, l0v = 1;
        void* args[] = {&xi_p, &wh_p, &bh_p, &hb_p, &hs_p, &h1_p, &st_p,
                        &t0v, &Tcv, &l0v};
        hipLaunchCooperativeKernel(gru_scan, dim3(256), dim3(512), args, 0, stream);
    }
    // layer 1
    for (int c = 0; c < nChunk; ++c) {
        int t0 = c * Tc;
        gemm_xi<512, false><<<dim3(24, Tc / 2), 256, 0, stream>>>(
            (const void*)h0seq, Wi1t, bi1, xibuf, t0, lgTc);
        const u16* xi_p = xibuf; const uint4* wh_p = Wh1p; const float* bh_p = bhn1;
        u32* hb_p = Hb1; u16* hs_p = nullptr; float* h1_p = h1last;
        float* st_p = hstate; int t0v = t0, Tcv = Tc, l0v = 0;
        void* args[] = {&xi_p, &wh_p, &bh_p, &hb_p, &hs_p, &h1_p, &st_p,
                        &t0v, &Tcv, &l0v};
        hipLaunchCooperativeKernel(gru_scan, dim3(256), dim3(512), args, 0, stream);
    }
    final_fc<<<32, 64, 0, stream>>>(h1last, Wfc, bfc, out);
}